// Round 13
// baseline (386.790 us; speedup 1.0000x reference)
//
#include <hip/hip_runtime.h>
#include <hip/hip_bf16.h>
#include <stdint.h>

// Problem dims (fixed by the reference setup_inputs):
//   a_previous [8192, 4096] f32, theta [4096, 4098] f32, aging [4096, 4098] f32
//   out [8192, 4096] f32
#define M_DIM 8192
#define N_DIM 4096
#define K_IN  4096          // n_in
#define NC    (K_IN + 2)    // 4098 theta/aging columns
#define K_DIM (2 * K_IN)    // GEMM K: [a | inv(a)] concatenated, i8 elems (= bytes)

#define BM 256
#define BN 256
#define BKB 128             // K-bytes per tile (i8) -> 128 B rows
#define NT (K_DIM / BKB)    // 64 K-tiles
#define NBLK (N_DIM / 32)   // 128 n-blocks in Bt layout

typedef __attribute__((ext_vector_type(4))) int i32x4;    // 16B A/B fragment
typedef __attribute__((ext_vector_type(16))) int i32x16;  // 32x32 acc

__device__ __forceinline__ float fast_tanh(float y) {
  float e = __expf(2.0f * y);
  return 1.0f - 2.0f * __builtin_amdgcn_rcpf(1.0f + e);
}

__device__ __forceinline__ int q8(float x) {   // round-to-nearest, fits i8 by range
  return (int)__builtin_rintf(x);
}

// ---------------------------------------------------------------------------
// prep_A: A' = [i8(a*127) | i8(inv(a)*127)], shape [8192][8192] i8
// ---------------------------------------------------------------------------
__global__ __launch_bounds__(256) void prep_A(const float* __restrict__ a,
                                              int8_t* __restrict__ Ap) {
  int idx = blockIdx.x * 256 + threadIdx.x;       // one float4 per thread
  int j  = idx >> 10;
  int k4 = (idx & 1023) << 2;
  float4 v = reinterpret_cast<const float4*>(a)[idx];
  float xs[4] = {v.x, v.y, v.z, v.w};
  int lw = 0, rw = 0;
#pragma unroll
  for (int t = 0; t < 4; ++t) {
    float x = xs[t];
    int ql = q8(x * 127.0f);
    float inv = 0.104f - 0.899f * fast_tanh((x + 0.056f) * 3.858f);
    int qr = q8(inv * 127.0f);
    lw |= (ql & 255) << (8 * t);
    rw |= (qr & 255) << (8 * t);
  }
  size_t base = (size_t)j * K_DIM + k4;
  *reinterpret_cast<int*>(Ap + base)        = lw;   // a half
  *reinterpret_cast<int*>(Ap + base + K_IN) = rw;   // inv(a) half
}

// ---------------------------------------------------------------------------
// prep_B: th = st(theta*aging); W = |th|/rowsum; per-row q8. Output is the
// FRAGMENT-LINEAR Bt layout consumed directly by the GEMM's global->VGPR B
// loads: for K-tile t (128 K-bytes), n-block nb (32 cols), ks (32 K-bytes):
// a 1024-B block at ((t*128+nb)<<12)+(ks<<10) where byte lane*16 holds the
// 16 K-bytes of col (lane&31), k-half (lane>>5) -- exactly the
// mfma_i32_32x32x32_i8 B operand for lane `lane`. Wn goes at t+32 (k+4096).
// corr[i] f32 exact; sc[i] dequant scale.
// ---------------------------------------------------------------------------
__global__ __launch_bounds__(256) void prep_B(const float* __restrict__ theta,
                                              const float* __restrict__ aging,
                                              int8_t* __restrict__ Bt,
                                              float* __restrict__ corr,
                                              float* __restrict__ sc) {
  __shared__ float th_s[NC];
  __shared__ float red_s[256];
  __shared__ float red_m[256];
  int i = blockIdx.x;            // output column i of the GEMM (B' row i)
  int tid = threadIdx.x;
  const float* tr = theta + (size_t)i * NC;
  const float* ar = aging + (size_t)i * NC;
  float psum = 0.f, pmax = 0.f;
  for (int k = tid; k < NC; k += 256) {
    float th = tr[k] * ar[k];
    if (fabsf(th) < 0.01f) th = 0.f;
    th_s[k] = th;
    psum += fabsf(th);
    if (k < K_IN) pmax = fmaxf(pmax, fabsf(th));
  }
  red_s[tid] = psum;
  red_m[tid] = pmax;
  __syncthreads();
  for (int s = 128; s > 0; s >>= 1) {
    if (tid < s) {
      red_s[tid] += red_s[tid + s];
      red_m[tid] = fmaxf(red_m[tid], red_m[tid + s]);
    }
    __syncthreads();
  }
  float inv_sum = 1.0f / red_s[0];
  float maxabs  = red_m[0];
  float qs = 127.0f / maxabs;
  const int nb = i >> 5;         // n-block
  const int li = i & 31;         // lane-in-block (col within 32)
  for (int k0 = tid * 4; k0 < K_IN; k0 += 1024) {
    int pw = 0, nw = 0;
#pragma unroll
    for (int t = 0; t < 4; ++t) {
      float th = th_s[k0 + t];
      int q = q8(fabsf(th) * qs);
      if (th >= 0.f) pw |= (q & 255) << (8 * t);
      else           nw |= (q & 255) << (8 * t);
    }
    const int t8  = k0 >> 7;             // K-tile (Wp side)
    const int ks  = (k0 >> 5) & 3;
    const int kg  = (k0 >> 4) & 1;
    const size_t byte_p = ((size_t)(t8 * 128 + nb) << 12) + (ks << 10)
                        + ((kg * 32 + li) << 4) + (k0 & 15);
    *reinterpret_cast<int*>(Bt + byte_p) = pw;                       // Wp (k)
    *reinterpret_cast<int*>(Bt + byte_p + ((size_t)4096 << 12)) = nw; // Wn (k+4096: t8+32)
  }
  if (tid == 0) {
    float th1 = th_s[K_IN];
    float th2 = th_s[K_IN + 1];
    float w1 = fabsf(th1) * inv_sum;
    float w2 = fabsf(th2) * inv_sum;
    float inv1 = 0.104f - 0.899f * fast_tanh((1.0f + 0.056f) * 3.858f);
    float inv0 = 0.104f - 0.899f * fast_tanh((0.0f + 0.056f) * 3.858f);
    float c = (th1 >= 0.f) ? w1 : w1 * inv1;
    c += (th2 >= 0.f) ? 0.0f : w2 * inv0;
    corr[i] = c;
    sc[i] = maxabs * inv_sum * (1.0f / 16129.0f);   // 1/(127*127)
  }
}

// ---------------------------------------------------------------------------
// gemm_fused (i8, 32x32x32): B OUT OF LDS (R12 post-mortem: LDS port carried
// 256 KB/K-tile (3x-amplified frag reads + glds writes) ~= matrix-pipe time;
// every schedule hit the serial sum). B frags now load global->VGPR from the
// fragment-linear Bt layout (1KB perfectly-coalesced loads, single-buffered:
// bn0(W+1) issued after M0 frees bn0, bn1(W+1) after M1 -- each >=1/2-tile
// lead; compiler emits the reg-load vmcnt waits). LDS carries only A:
// 160 KB/tile (was 256), now < matrix time. 2 clusters/tile split by n
// (M0 = m0-3 x n0, M1 = m0-3 x n1), ONE barrier per tile.
// asm vmcnt = glds->ds_read gate only: p0 vmcnt(8) [newer: A(W+1)glds4 +
// bn1(W)4], p1 vmcnt(4) pre-barrier [newer: bn0(W+1)4 -> A(W+1) glds landed
// before a(W+1) reads]. Tail: p0 vmcnt(4) @NT-1; p1 vmcnt(0) @NT-1.
// Ledger: buf(W&1) A last read-issued at W-1 p1 (a(W)), consumed by M0/M1,
// lgkm0+barrier at W p1; stage A(W+2)->buf after that barrier. a(W+1) reads
// target buf^1 (disjoint). sched_barrier(0) after each cluster forces reg
// reuse (a, bn single-buffered -> ~125 VGPR, no spill at 2-wave/SIMD cap).
// Swizzle involution (A only) + epilogue unchanged (R9-verified).
// ---------------------------------------------------------------------------
__global__ __launch_bounds__(512, 2) void gemm_fused(const int8_t* __restrict__ A,
                                                     const int8_t* __restrict__ Bt,
                                                     const float* __restrict__ corr,
                                                     const float* __restrict__ sc,
                                                     float* __restrict__ C) {
  extern __shared__ char lds[];   // 65536 B: 2 buf x 32 KB (A only)
  const int tid  = threadIdx.x;
  const int lane = tid & 63;
  const int wid  = tid >> 6;     // 0..7
  const int wr   = wid >> 2;     // 0..1  -> M offset wr*128
  const int wc   = wid & 3;      // 0..3  -> N offset wc*64
  const int fr   = lane & 31;    // fragment row/col (32-row tiles)
  const int kg   = lane >> 5;    // k-group 0/1 (16B each)

  // T1: XCD-aware swizzle; nwg = 512, divisible by 8 -> bijective
  const int bid = (int)blockIdx.x;
  const int sw  = (bid & 7) * 64 + (bid >> 3);
  const int bm0 = (sw >> 4) * BM;     // 32 M-blocks
  const int bn0 = (sw & 15) * BN;     // 16 N-blocks

  // A staging: linear LDS dest (glds); GLOBAL source slot pre-swizzled with
  // the involution of the read XOR (R9-verified: 0 conflicts, absmax 0)
  const int colsw = (((tid & 7) ^ ((tid >> 3) & 7) ^ ((tid >> 6) & 3)) << 4);
  const int8_t* gA = A + (size_t)(bm0 + (tid >> 3)) * K_DIM + colsw;
  const int dst_t = tid * 16;

  // A read-side swizzled fragment byte offsets (within a 128B row)
  const int flip = (((fr & 7) ^ ((fr >> 3) & 3)) << 4);
  int csk[4];
#pragma unroll
  for (int ks = 0; ks < 4; ++ks) csk[ks] = (ks * 32 + kg * 16) ^ flip;
  const int aRow = (wr * 128 + fr) * BKB;   // frag base row byte offset in buf

  // B: per-wave-lane base into fragment-linear Bt; block idx = W*128 + nb0 + n
  const int nb0 = (bn0 >> 5) + wc * 2;
  const int8_t* gBt = Bt + ((size_t)nb0 << 12) + lane * 16;

  i32x16 acc[4][2] = {};   // [m-tile][n-tile]
  i32x4 a[4][4];           // A frags, single-buffered (64 VGPR)
  i32x4 bn[2][4];          // B frags n0/n1, single-buffered (32 VGPR)

#define STAGE_A(T) do {                                                              \
    char* _lb = lds + ((T) & 1) * 32768;                                             \
    const size_t _go = (size_t)(T) * BKB;                                            \
    _Pragma("unroll")                                                                \
    for (int _q = 0; _q < 4; ++_q)                                                   \
      __builtin_amdgcn_global_load_lds(                                              \
          (const __attribute__((address_space(1))) unsigned int*)(gA + _go + (size_t)_q * 64 * K_DIM), \
          (__attribute__((address_space(3))) unsigned int*)(_lb + _q * 8192 + dst_t), 16, 0, 0); \
  } while (0)

#define LOADB(dst, T, n) do {                                                        \
    _Pragma("unroll")                                                                \
    for (int _ks = 0; _ks < 4; ++_ks)                                                \
      dst[_ks] = *(const i32x4*)(gBt + (((size_t)(T) * 128 + (n)) << 12) + (_ks << 10)); \
  } while (0)

#define READ_A(T) do {                                                               \
    const char* _pa = lds + ((T) & 1) * 32768 + aRow;                                \
    _Pragma("unroll")                                                                \
    for (int _m = 0; _m < 4; ++_m)                                                   \
      _Pragma("unroll")                                                              \
      for (int _ks = 0; _ks < 4; ++_ks)                                              \
        a[_m][_ks] = *(const i32x4*)(_pa + _m * 32 * BKB + csk[_ks]);                \
  } while (0)

#define MFMA32(x, y, c) __builtin_amdgcn_mfma_i32_32x32x32_i8((x), (y), (c), 0, 0, 0)

  // ---- prologue: stage A(0),A(1) (8 glds); load B(0); drain; read a(0)
  STAGE_A(0); STAGE_A(1);
  LOADB(bn[0], 0, 0); LOADB(bn[1], 0, 1);
  asm volatile("s_waitcnt vmcnt(0)" ::: "memory");
  __builtin_amdgcn_s_barrier();
  asm volatile("" ::: "memory");
  READ_A(0);

#pragma unroll 2
  for (int W = 0; W < NT; ++W) {
    // ===== p0: M0 = m0-3 x n0; then reload bn0 <- (W+1)
    if (W < NT - 1) { asm volatile("s_waitcnt vmcnt(8)" ::: "memory"); }
    else            { asm volatile("s_waitcnt vmcnt(4)" ::: "memory"); }
    __builtin_amdgcn_s_setprio(1);
#pragma unroll
    for (int ks = 0; ks < 4; ++ks)
#pragma unroll
      for (int m = 0; m < 4; ++m)
        acc[m][0] = MFMA32(a[m][ks], bn[0][ks], acc[m][0]);
    __builtin_amdgcn_s_setprio(0);
    __builtin_amdgcn_sched_barrier(0);          // force bn0 reg reuse
    if (W + 1 < NT) LOADB(bn[0], W + 1, 0);

    // ===== p1: gate A(W+1) landed; barrier; M1 = m0-3 x n1; then refill
    if (W < NT - 1) { asm volatile("s_waitcnt vmcnt(4)" ::: "memory"); }
    else            { asm volatile("s_waitcnt vmcnt(0)" ::: "memory"); }
    asm volatile("s_waitcnt lgkmcnt(0)" ::: "memory");
    __builtin_amdgcn_s_barrier();
    asm volatile("" ::: "memory");
    __builtin_amdgcn_s_setprio(1);
#pragma unroll
    for (int ks = 0; ks < 4; ++ks)
#pragma unroll
      for (int m = 0; m < 4; ++m)
        acc[m][1] = MFMA32(a[m][ks], bn[1][ks], acc[m][1]);
    __builtin_amdgcn_s_setprio(0);
    __builtin_amdgcn_sched_barrier(0);          // force a/bn1 reg reuse
    if (W + 1 < NT) READ_A(W + 1);              // ds_reads overlap next M0 wait
    if (W + 2 < NT) STAGE_A(W + 2);             // glds -> buf (ledger: post-barrier)
    if (W + 1 < NT) LOADB(bn[1], W + 1, 1);
  }

  // ---- epilogue: z = acc*sc[n] + corr[n]; activation; store
  // C/D layout (32x32): col = lane&31, row = (reg&3) + 8*(reg>>2) + 4*(lane>>5)
#pragma unroll
  for (int n = 0; n < 2; ++n) {
    const int col = bn0 + wc * 64 + n * 32 + fr;
    const float cr = corr[col];
    const float s  = sc[col];
#pragma unroll
    for (int mi = 0; mi < 4; ++mi) {
      const int rbase = bm0 + wr * 128 + mi * 32 + 4 * kg;
#pragma unroll
      for (int r = 0; r < 16; ++r) {
        const int row = rbase + (r & 3) + 8 * (r >> 2);
        float z = (float)acc[mi][n][r] * s + cr;
        float e = __expf((z - 0.183f) * 48.2f);
        C[(size_t)row * N_DIM + col] = 1.096f - 1.924f * __builtin_amdgcn_rcpf(1.0f + e);
      }
    }
  }
#undef STAGE_A
#undef LOADB
#undef READ_A
#undef MFMA32
}

// ---------------------------------------------------------------------------
extern "C" void kernel_launch(void* const* d_in, const int* in_sizes, int n_in,
                              void* d_out, int out_size, void* d_ws, size_t ws_size,
                              hipStream_t stream) {
  (void)in_sizes; (void)n_in; (void)out_size; (void)ws_size;
  const float* a_prev = (const float*)d_in[0];
  const float* theta  = (const float*)d_in[1];
  const float* aging  = (const float*)d_in[2];
  float* out = (float*)d_out;

  char* ws = (char*)d_ws;
  int8_t* Ap = (int8_t*)ws;                                        // 64 MiB
  int8_t* Bt = (int8_t*)(ws + (size_t)M_DIM * K_DIM);              // 32 MiB
  float* corr = (float*)(ws + (size_t)M_DIM * K_DIM + (size_t)N_DIM * K_DIM);
  float* sc   = corr + N_DIM;

  prep_A<<<(M_DIM * K_IN / 4) / 256, 256, 0, stream>>>(a_prev, Ap);
  prep_B<<<N_DIM, 256, 0, stream>>>(theta, aging, Bt, corr, sc);

  (void)hipFuncSetAttribute((const void*)gemm_fused,
                            hipFuncAttributeMaxDynamicSharedMemorySize, 65536);
  gemm_fused<<<dim3((M_DIM / BM) * (N_DIM / BN)), dim3(512), 65536, stream>>>(Ap, Bt, corr, sc, out);
}